// Round 1
// baseline (1696.038 us; speedup 1.0000x reference)
//
#include <hip/hip_runtime.h>
#include <stdint.h>

// Constrained Viterbi decode, B=64, T=2048, N=32.
// One fused kernel: 64 blocks (1 per batch), 256 threads (4 waves):
//   wave0  : exact sequential alpha recurrence (bit-exact vs reference)
//   wave1-3: HBM prefetch (12 steps deep) + eff formation + backpointer argmax
// Backpointers live entirely in LDS; backtrack fused at the end of the block.

static constexpr int TT = 2048;
static constexpr int RING = 6;            // eff tile ring (LDS)
static constexpr int RS = 36;             // padded eff row stride (dwords), 144B rows (16B aligned)
static constexpr int TILE_DW = 32 * RS;   // 1152 dwords per tile
static constexpr int OFF_EFF   = 0;                         // 6*4608 = 27648 B
static constexpr int OFF_ALPHA = RING * TILE_DW * 4;        // 27648, 16 slots * 32 f32 = 2048 B
static constexpr int OFF_BACK  = OFF_ALPHA + 16 * 32 * 4;   // 29696, 2048*32 u8 = 65536 B
static constexpr int OFF_MAPS  = OFF_BACK + TT * 32;        // 95232, 32*32 u8
static constexpr int OFF_EV    = OFF_MAPS + 32 * 32;        // 96256, 32 int
static constexpr int OFF_FLAGS = OFF_EV + 32 * 4;           // 96384
static constexpr int SMEM_BYTES = OFF_FLAGS + 64;           // 96448 B total

#define NINF_ (-1e4f)

__device__ __forceinline__ int bperm_i(int srclane, int v) {
  return __builtin_amdgcn_ds_bpermute(srclane << 2, v);
}
__device__ __forceinline__ float bperm_f(int srclane, float v) {
  return __int_as_float(__builtin_amdgcn_ds_bpermute(srclane << 2, __float_as_int(v)));
}

// spin until *p >= w (LDS flag; all lanes read same address -> uniform branch)
#define POLL_GE(p, w) do { while (*(p) < (w)) { } __asm__ __volatile__("" ::: "memory"); } while (0)
// drain LDS ops only (lgkmcnt(0)); vmcnt left untouched so global prefetches stay in flight.
// imm = vmcnt_lo(15) | expcnt(7)<<4 | lgkmcnt(0)<<8 | vmcnt_hi(3)<<14 = 0xC07F
#define LGKM0() do { __builtin_amdgcn_s_waitcnt(0xC07F); __asm__ __volatile__("" ::: "memory"); } while (0)

extern "C" __global__ void __launch_bounds__(256, 1)
viterbi_fused(const float* __restrict__ lp, const int* __restrict__ mask,
              const int* __restrict__ startc, const int* __restrict__ endc,
              const int* __restrict__ transc, float* __restrict__ out)
{
  extern __shared__ char smem[];
  float*   effT   = (float*)(smem + OFF_EFF);
  float*   alphaH = (float*)(smem + OFF_ALPHA);
  uint8_t* back   = (uint8_t*)(smem + OFF_BACK);
  uint8_t* maps   = (uint8_t*)(smem + OFF_MAPS);
  int*     Ev     = (int*)(smem + OFF_EV);
  volatile int* flags = (volatile int*)(smem + OFF_FLAGS);
  int*     flags_nv   = (int*)(smem + OFF_FLAGS);
  // flags: [0..2]=eff_ready per worker, [3]=prog_w0, [4..6]=wprog, [7]=len, [8]=last_tag

  const int b   = blockIdx.x;
  const int tid = threadIdx.x;
  const int wid = tid >> 6;
  const int l   = tid & 63;
  const int j   = l & 31;   // column / tag index
  const int h   = l >> 5;   // which half of i-range this lane covers

  if (tid < 16) flags_nv[tid] = 0;
  __syncthreads();
  {
    int s = 0;
#pragma unroll
    for (int k = 0; k < 8; ++k) s += mask[b * TT + k * 256 + tid];
    atomicAdd(&flags_nv[7], s);   // prefix-true mask -> sum == length
  }
  __syncthreads();
  const int len = flags_nv[7];

  const float epj = endc[j] ? 0.0f : NINF_;

  if (wid == 0) {
    // ================== recurrence wave ==================
    POLL_GE(&flags[0], 1);   // eff tile 0 (includes start_pen) ready
    {
      const float* rp = effT + j * RS + h * 16;
      float4 e0 = *(const float4*)(rp + 0);
      float4 e1 = *(const float4*)(rp + 4);
      float4 e2 = *(const float4*)(rp + 8);
      float4 e3 = *(const float4*)(rp + 12);
      float m = fmaxf(
          fmaxf(fmaxf(fmaxf(e0.x, e0.y), fmaxf(e0.z, e0.w)),
                fmaxf(fmaxf(e1.x, e1.y), fmaxf(e1.z, e1.w))),
          fmaxf(fmaxf(fmaxf(e2.x, e2.y), fmaxf(e2.z, e2.w)),
                fmaxf(fmaxf(e3.x, e3.y), fmaxf(e3.z, e3.w))));
      m = fmaxf(m, bperm_f(l ^ 32, m));
      if (l < 32) alphaH[l] = m;   // alpha_0
      LGKM0();
      if (tid == 0) flags[3] = 1;
    }
    for (int t = 1; t < len; ++t) {
      if ((t & 3) == 0 && t >= 16) {           // alphaH ring overwrite guard
        POLL_GE(&flags[4], t - 11);
        POLL_GE(&flags[5], t - 11);
        POLL_GE(&flags[6], t - 11);
      }
      if (t % 3 == 1) {                        // amortized eff-ready polls (covers t..t+2)
        POLL_GE(&flags[1], t + 1);
        if (t + 1 < len) POLL_GE(&flags[2], t + 2);
        if (t + 2 < len) POLL_GE(&flags[0], t + 3);
      }
      const float* ap = alphaH + ((t - 1) & 15) * 32 + h * 16;
      float4 a0 = *(const float4*)(ap + 0);
      float4 a1 = *(const float4*)(ap + 4);
      float4 a2 = *(const float4*)(ap + 8);
      float4 a3 = *(const float4*)(ap + 12);
      const float* rp = effT + (t % RING) * TILE_DW + j * RS + h * 16;
      float4 e0 = *(const float4*)(rp + 0);
      float4 e1 = *(const float4*)(rp + 4);
      float4 e2 = *(const float4*)(rp + 8);
      float4 e3 = *(const float4*)(rp + 12);
      float c0 = a0.x + e0.x, c1 = a0.y + e0.y, c2 = a0.z + e0.z, c3 = a0.w + e0.w;
      float c4 = a1.x + e1.x, c5 = a1.y + e1.y, c6 = a1.z + e1.z, c7 = a1.w + e1.w;
      float c8 = a2.x + e2.x, c9 = a2.y + e2.y, cA = a2.z + e2.z, cB = a2.w + e2.w;
      float cC = a3.x + e3.x, cD = a3.y + e3.y, cE = a3.z + e3.z, cF = a3.w + e3.w;
      float m = fmaxf(
          fmaxf(fmaxf(fmaxf(c0, c1), fmaxf(c2, c3)), fmaxf(fmaxf(c4, c5), fmaxf(c6, c7))),
          fmaxf(fmaxf(fmaxf(c8, c9), fmaxf(cA, cB)), fmaxf(fmaxf(cC, cD), fmaxf(cE, cF))));
      m = fmaxf(m, bperm_f(l ^ 32, m));
      if (l < 32) alphaH[(t & 15) * 32 + l] = m;
      LGKM0();
      if (tid == 0) flags[3] = t + 1;
    }
  } else {
    // ================== worker waves (t mod 3 == wk) ==================
    const int wk = wid - 1;
    float tp[16];
#pragma unroll
    for (int k = 0; k < 16; ++k) tp[k] = transc[(16 * h + k) * 32 + j] ? 0.0f : NINF_;
    const float spj = startc[j] ? 0.0f : NINF_;
    const float* gb = lp + (size_t)b * TT * 1024 + (size_t)(16 * h * 32 + j);
    float buf[4][16];   // 4 tiles in flight (12-step lookahead)
#pragma unroll
    for (int s = 0; s < 4; ++s) {
      const int tl = wk + 3 * s;
      if (tl < len) {
        const float* g = gb + (size_t)tl * 1024;
#pragma unroll
        for (int k = 0; k < 16; ++k) buf[s][k] = g[k * 32];
      }
    }
    for (int base = wk; base < len; base += 12) {
#pragma unroll
      for (int s = 0; s < 4; ++s) {
        const int t = base + 3 * s;
        if (t < len) {
          // ---- form eff = (phi + trans_pen)(+ end_pen at t==len-1); t==0 uses start_pen ----
          float e[16];
          if (t == 0) {
#pragma unroll
            for (int k = 0; k < 16; ++k) e[k] = buf[s][k] + spj;
          } else {
#pragma unroll
            for (int k = 0; k < 16; ++k) e[k] = buf[s][k] + tp[k];
          }
          if (t == len - 1) {
#pragma unroll
            for (int k = 0; k < 16; ++k) e[k] += epj;
          }
          if (t >= RING) POLL_GE(&flags[3], t - (RING - 1));   // eff slot reuse guard
          float* rp = effT + (t % RING) * TILE_DW + j * RS + h * 16;
          *(float4*)(rp + 0)  = make_float4(e[0],  e[1],  e[2],  e[3]);
          *(float4*)(rp + 4)  = make_float4(e[4],  e[5],  e[6],  e[7]);
          *(float4*)(rp + 8)  = make_float4(e[8],  e[9],  e[10], e[11]);
          *(float4*)(rp + 12) = make_float4(e[12], e[13], e[14], e[15]);
          LGKM0();
          if (l == 0) flags[wk] = t + 1;    // release eff_t (never blocks on w0)
          // ---- backpointer argmax (first-index ties, matches jnp.argmax) ----
          if (t >= 1) {
            POLL_GE(&flags[3], t);          // need alpha_{t-1}
            const float* ap = alphaH + ((t - 1) & 15) * 32 + h * 16;
            float4 a0 = *(const float4*)(ap + 0);
            float4 a1 = *(const float4*)(ap + 4);
            float4 a2 = *(const float4*)(ap + 8);
            float4 a3 = *(const float4*)(ap + 12);
            float av[16];
            av[0]=a0.x; av[1]=a0.y; av[2]=a0.z; av[3]=a0.w;
            av[4]=a1.x; av[5]=a1.y; av[6]=a1.z; av[7]=a1.w;
            av[8]=a2.x; av[9]=a2.y; av[10]=a2.z; av[11]=a2.w;
            av[12]=a3.x; av[13]=a3.y; av[14]=a3.z; av[15]=a3.w;
            float bv = av[0] + e[0]; int bi = 0;
#pragma unroll
            for (int k = 1; k < 16; ++k) {
              float c = av[k] + e[k];
              if (c > bv) { bv = c; bi = k; }   // strict > keeps first max
            }
            float ob = bperm_f(l ^ 32, bv);
            int   oi = bperm_i(l ^ 32, bi);
            int bk = (ob > bv) ? (oi + 16) : bi;  // lanes h==0: other half only wins strictly
            if (l < 32) back[(size_t)t * 32 + l] = (uint8_t)bk;
          }
          LGKM0();
          if (l == 0) flags[4 + wk] = t + 3;  // wprog = next own t
          // ---- refill this slot (t+12) ----
          const int tn = t + 12;
          if (tn < len) {
            const float* g = gb + (size_t)tn * 1024;
#pragma unroll
            for (int k = 0; k < 16; ++k) buf[s][k] = g[k * 32];
          }
        }
      }
    }
  }
  __syncthreads();

  // ================== epilogue: mlp + last_tag ==================
  if (wid == 0) {
    float v = alphaH[((len - 1) & 15) * 32 + j];
    int idx = j;
#pragma unroll
    for (int d = 1; d <= 16; d <<= 1) {
      float ov = bperm_f(l ^ d, v);
      int   oi = bperm_i(l ^ d, idx);
      if (ov > v || (ov == v && oi < idx)) { v = ov; idx = oi; }  // first-index argmax
    }
    if (tid == 0) { out[b] = v; flags_nv[8] = idx; }
  }
  __syncthreads();
  const int last_tag = flags_nv[8];

  // ---- Phase A: per-chunk backpointer map composition (32 chunks of 64, 8/wave interleaved) ----
  int M[8];
#pragma unroll
  for (int m = 0; m < 8; ++m) M[m] = j;
  for (int kk = 63; kk >= 0; --kk) {
#pragma unroll
    for (int m = 0; m < 8; ++m) {
      const int c = wid * 8 + m;
      const int t = c * 64 + kk;
      if (t >= 1 && t < len) {             // t>=len: identity (masked steps)
        int bt = back[t * 32 + j];
        M[m] = bperm_i(M[m], bt);          // M <- back_t[M]
      }
    }
  }
#pragma unroll
  for (int m = 0; m < 8; ++m) if (l < 32) maps[(wid * 8 + m) * 32 + l] = (uint8_t)M[m];
  __syncthreads();

  // ---- Phase B: stitch chunk-boundary tags (serial, 31 LDS hops) ----
  if (tid == 0) {
    int e = last_tag;
    Ev[31] = e;
    for (int c = 31; c >= 1; --c) { e = maps[c * 32 + e]; Ev[c - 1] = e; }
  }
  __syncthreads();

  // ---- Phase C: replay within chunks, emit tags ----
  int tg[8], kp[8];
#pragma unroll
  for (int m = 0; m < 8; ++m) { tg[m] = Ev[wid * 8 + m]; kp[m] = tg[m]; }
  for (int kk = 63; kk >= 0; --kk) {
#pragma unroll
    for (int m = 0; m < 8; ++m) {
      const int c = wid * 8 + m;
      const int p = c * 64 + kk;
      kp[m] = (l == kk) ? tg[m] : kp[m];   // lane kk keeps tag@p
      if (p >= 1 && p < len) {
        int bt = back[p * 32 + j];
        tg[m] = bperm_i(tg[m], bt);        // tag@(p-1) = back_p[tag@p]
      }
    }
  }
#pragma unroll
  for (int m = 0; m < 8; ++m) {
    const int c = wid * 8 + m;
    const int pos = c * 64 + l;
    out[64 + b * TT + pos] = (pos < len) ? (float)kp[m] : -1.0f;
  }
}

extern "C" void kernel_launch(void* const* d_in, const int* in_sizes, int n_in,
                              void* d_out, int out_size, void* d_ws, size_t ws_size,
                              hipStream_t stream) {
  const float* lp     = (const float*)d_in[0];
  const int*   mask   = (const int*)d_in[1];
  const int*   startc = (const int*)d_in[2];
  const int*   endc   = (const int*)d_in[3];
  const int*   transc = (const int*)d_in[4];
  float* out = (float*)d_out;
  (void)d_ws; (void)ws_size; (void)n_in; (void)in_sizes; (void)out_size;
  hipFuncSetAttribute((const void*)viterbi_fused,
                      hipFuncAttributeMaxDynamicSharedMemorySize, SMEM_BYTES);
  viterbi_fused<<<dim3(64), dim3(256), SMEM_BYTES, stream>>>(lp, mask, startc, endc, transc, out);
}

// Round 2
// 1449.083 us; speedup vs baseline: 1.1704x; 1.1704x over previous
//
#include <hip/hip_runtime.h>
#include <stdint.h>

// Constrained Viterbi decode, B=64, T=2048, N=32. 64 blocks x 256 threads.
// wave0: serial alpha recurrence, alpha kept in 32 SGPRs (v_readlane), eff
//        prefetched from LDS ring one step ahead. No per-step cross-wave wait.
// waves1-3: HBM prefetch -> eff tiles (16-slot LDS ring, ~8-15 steps ahead of
//        wave0) + lazy backpointer drain (vs 32-slot alpha history ring).
// Sync: wave0 publishes progress every 4 steps, polls batched flags every 8.

static constexpr int TT = 2048;
static constexpr int RING = 16;            // eff ring slots (power of 2)
static constexpr int CS = 36;              // col stride (dwords): 144B, 16B-aligned
static constexpr int TILE_DW = 32 * CS;    // 1152 dwords / tile
static constexpr int OFF_EFF   = 0;                          // 16*4608 = 73728 B
static constexpr int OFF_ALPHA = RING * TILE_DW * 4;         // 73728; 32 slots * 32 f32
static constexpr int OFF_BACK  = OFF_ALPHA + 32 * 32 * 4;    // 77824; 2048*32 u8
static constexpr int OFF_MAPS  = OFF_BACK + TT * 32;         // 143360
static constexpr int OFF_EV    = OFF_MAPS + 32 * 32;         // 144384
static constexpr int OFF_FLAGS = OFF_EV + 32 * 4;            // 144512
static constexpr int SMEM_BYTES = OFF_FLAGS + 64;            // 144576 B

#define NINF_ (-1e4f)

__device__ __forceinline__ int bperm_i(int srclane, int v) {
  return __builtin_amdgcn_ds_bpermute(srclane << 2, v);
}
__device__ __forceinline__ float bperm_f(int srclane, float v) {
  return __int_as_float(__builtin_amdgcn_ds_bpermute(srclane << 2, __float_as_int(v)));
}
// drain LDS ops only (lgkmcnt(0)); vmcnt untouched so global prefetches stay in flight.
#define LGKM0() do { __builtin_amdgcn_s_waitcnt(0xC07F); __asm__ __volatile__("" ::: "memory"); } while (0)
#define MEMBAR() __asm__ __volatile__("" ::: "memory")

// flags: [0]=wave0 published progress (steps completed), [1..3]=eff flag per
// worker (last own tau done +1), [4..6]=bp sigma_next per worker, [7]=len, [8]=last_tag

// one wave0 recurrence step: CUR = eff_t regs, NXT <- eff_{t+1} prefetch
#define W0_STEP(CUR, NXT)                                                      \
  do {                                                                         \
    if ((t & 7) == 0) {                                                        \
      LGKM0();                                                                 \
      if (tid == 0) flags[0] = t;                                              \
      const int ne = (t + 9 < len - 2) ? (t + 9) : (len - 2);                  \
      const int nb = t - 20;                                                   \
      for (;;) {                                                               \
        int f1 = flags_nv[1], f2 = flags_nv[2], f3 = flags_nv[3];              \
        int b1 = flags_nv[4], b2 = flags_nv[5], b3 = flags_nv[6];              \
        MEMBAR();                                                              \
        if (f1 >= ne && f2 >= ne && f3 >= ne &&                                \
            b1 >= nb && b2 >= nb && b3 >= nb) break;                           \
      }                                                                        \
    } else if ((t & 3) == 0) {                                                 \
      LGKM0();                                                                 \
      if (tid == 0) flags[0] = t;                                              \
    }                                                                          \
    if (t + 1 < len) {                                                         \
      const float* np_ = effT + ((t + 1) & (RING - 1)) * TILE_DW + jj * CS;    \
      _Pragma("unroll")                                                        \
      for (int q = 0; q < 8; ++q) NXT[q] = *(const float4*)(np_ + 4 * q);      \
    }                                                                          \
    float qm[8];                                                               \
    _Pragma("unroll")                                                          \
    for (int q = 0; q < 8; ++q)                                                \
      qm[q] = fmaxf(fmaxf(sa[4*q+0] + CUR[q].x, sa[4*q+1] + CUR[q].y),         \
                    fmaxf(sa[4*q+2] + CUR[q].z, sa[4*q+3] + CUR[q].w));        \
    float m_ = fmaxf(fmaxf(fmaxf(qm[0], qm[1]), fmaxf(qm[2], qm[3])),          \
                     fmaxf(fmaxf(qm[4], qm[5]), fmaxf(qm[6], qm[7])));         \
    alphaH[(t & 31) * 32 + jj] = m_;                                           \
    int mi_ = __float_as_int(m_);                                              \
    _Pragma("unroll")                                                          \
    for (int i = 0; i < 32; ++i)                                               \
      sa[i] = __int_as_float(__builtin_amdgcn_readlane(mi_, i));               \
  } while (0)

extern "C" __global__ void __launch_bounds__(256, 1)
viterbi_fused(const float* __restrict__ lp, const int* __restrict__ mask,
              const int* __restrict__ startc, const int* __restrict__ endc,
              const int* __restrict__ transc, float* __restrict__ out)
{
  extern __shared__ char smem[];
  float*   effT   = (float*)(smem + OFF_EFF);
  float*   alphaH = (float*)(smem + OFF_ALPHA);
  uint8_t* back   = (uint8_t*)(smem + OFF_BACK);
  uint8_t* maps   = (uint8_t*)(smem + OFF_MAPS);
  int*     Ev     = (int*)(smem + OFF_EV);
  volatile int* flags = (volatile int*)(smem + OFF_FLAGS);
  int*     flags_nv   = (int*)(smem + OFF_FLAGS);

  const int b   = blockIdx.x;
  const int tid = threadIdx.x;
  const int wid = tid >> 6;
  const int l   = tid & 63;
  const int j   = l & 31;
  const int h   = l >> 5;

  if (tid < 16) flags_nv[tid] = 0;
  __syncthreads();
  {
    int s = 0;
#pragma unroll
    for (int k = 0; k < 8; ++k) s += mask[b * TT + k * 256 + tid];
    atomicAdd(&flags_nv[7], s);   // prefix-true mask -> sum == length
  }
  __syncthreads();
  const int len = flags_nv[7];
  const float epj = endc[j] ? 0.0f : NINF_;

  if (wid == 0) {
    // ================== recurrence wave (32-lane mirrored, alpha in SGPRs) ==
    const int jj = j;
    float  sa[32];
    float4 eA[8], eB[8];
    {  // initial poll: eff_0..eff_8 ready
      const int need = (9 < len - 2) ? 9 : (len - 2);
      for (;;) {
        int f1 = flags_nv[1], f2 = flags_nv[2], f3 = flags_nv[3];
        MEMBAR();
        if (f1 >= need && f2 >= need && f3 >= need) break;
      }
    }
    {
      const float* p0 = effT + jj * CS;
#pragma unroll
      for (int q = 0; q < 8; ++q) eA[q] = *(const float4*)(p0 + 4 * q);
      const float* p1 = effT + TILE_DW + jj * CS;
#pragma unroll
      for (int q = 0; q < 8; ++q) eB[q] = *(const float4*)(p1 + 4 * q);
    }
    {  // t = 0: alpha0 = colmax(eff0), no alpha add
      float qm[8];
#pragma unroll
      for (int q = 0; q < 8; ++q)
        qm[q] = fmaxf(fmaxf(eA[q].x, eA[q].y), fmaxf(eA[q].z, eA[q].w));
      float m = fmaxf(fmaxf(fmaxf(qm[0], qm[1]), fmaxf(qm[2], qm[3])),
                      fmaxf(fmaxf(qm[4], qm[5]), fmaxf(qm[6], qm[7])));
      alphaH[jj] = m;
      int mi = __float_as_int(m);
#pragma unroll
      for (int i = 0; i < 32; ++i)
        sa[i] = __int_as_float(__builtin_amdgcn_readlane(mi, i));
    }
    int t = 1;
    while (t < len) {
      W0_STEP(eB, eA); ++t;
      if (t >= len) break;
      W0_STEP(eA, eB); ++t;
    }
    LGKM0();
    if (tid == 0) flags[0] = len;   // unblock final bp drains
  } else {
    // ================== worker waves: eff production + lazy bp drain ========
    const int wk = wid - 1;
    float tp[16];
#pragma unroll
    for (int k = 0; k < 16; ++k) tp[k] = transc[(16 * h + k) * 32 + j] ? 0.0f : NINF_;
    const float spj = startc[j] ? 0.0f : NINF_;
    const float* gb = lp + (size_t)b * TT * 1024 + (size_t)(16 * h * 32 + j);

    auto DO_BP = [&](int sg) {
      const float* ap = alphaH + ((sg - 1) & 31) * 32 + h * 16;
      float4 a0 = *(const float4*)(ap + 0), a1 = *(const float4*)(ap + 4),
             a2 = *(const float4*)(ap + 8), a3 = *(const float4*)(ap + 12);
      const float* ep = effT + (sg & (RING - 1)) * TILE_DW + j * CS + h * 16;
      float4 e0 = *(const float4*)(ep + 0), e1 = *(const float4*)(ep + 4),
             e2 = *(const float4*)(ep + 8), e3 = *(const float4*)(ep + 12);
      float av[16] = {a0.x,a0.y,a0.z,a0.w, a1.x,a1.y,a1.z,a1.w,
                      a2.x,a2.y,a2.z,a2.w, a3.x,a3.y,a3.z,a3.w};
      float ev[16] = {e0.x,e0.y,e0.z,e0.w, e1.x,e1.y,e1.z,e1.w,
                      e2.x,e2.y,e2.z,e2.w, e3.x,e3.y,e3.z,e3.w};
      float bv = av[0] + ev[0]; int bi = 0;
#pragma unroll
      for (int k = 1; k < 16; ++k) {
        float c = av[k] + ev[k];
        if (c > bv) { bv = c; bi = k; }      // strict > keeps first max
      }
      float ob = bperm_f(l ^ 32, bv);
      int   oi = bperm_i(l ^ 32, bi);
      int bk = (ob > bv) ? (oi + 16) : bi;   // upper half wins only strictly
      if (l < 32) back[(size_t)sg * 32 + l] = (uint8_t)bk;
    };

    float buf[4][16];   // HBM prefetch, 12-step lookahead
#pragma unroll
    for (int s = 0; s < 4; ++s) {
      const int tl = wk + 3 * s;
      if (tl < len) {
        const float* g = gb + (size_t)tl * 1024;
#pragma unroll
        for (int k = 0; k < 16; ++k) buf[s][k] = g[k * 32];
      }
    }
    int sigma = (wk == 0) ? 3 : wk;   // next own bp step
    const int pw = 4 + ((wk + 2) % 3);
    for (int base = wk; base < len; base += 12) {
#pragma unroll
      for (int s = 0; s < 4; ++s) {
        const int tau = base + 3 * s;
        if (tau < len) {
          const int needg = tau - 15;   // eff slot reuse: wave0 read + prev bp done
          if (needg > 0) {
            for (;;) {
              int f0 = flags_nv[0]; int bq = flags_nv[pw];
              MEMBAR();
              if (f0 >= needg && bq >= needg) break;
            }
          }
          while (sigma <= tau - 15) { DO_BP(sigma); sigma += 3; }  // mandatory drain
          // ---- form + write eff_tau ----
          float e[16];
          if (tau == 0) {
#pragma unroll
            for (int k = 0; k < 16; ++k) e[k] = buf[s][k] + spj;
          } else {
#pragma unroll
            for (int k = 0; k < 16; ++k) e[k] = buf[s][k] + tp[k];
          }
          if (tau == len - 1) {
#pragma unroll
            for (int k = 0; k < 16; ++k) e[k] += epj;
          }
          float* rp = effT + (tau & (RING - 1)) * TILE_DW + j * CS + h * 16;
          *(float4*)(rp + 0)  = make_float4(e[0],  e[1],  e[2],  e[3]);
          *(float4*)(rp + 4)  = make_float4(e[4],  e[5],  e[6],  e[7]);
          *(float4*)(rp + 8)  = make_float4(e[8],  e[9],  e[10], e[11]);
          *(float4*)(rp + 12) = make_float4(e[12], e[13], e[14], e[15]);
          LGKM0();
          if (l == 0) flags[1 + wk] = tau + 1;
          // ---- opportunistic bp drain (<=2) ----
          {
            int f0s = flags_nv[0];
            MEMBAR();
            int lim = (f0s < len - 1) ? f0s : (len - 1);
            if (lim > tau) lim = tau;
            int cnt = 0;
            while (cnt < 2 && sigma <= lim) { DO_BP(sigma); sigma += 3; ++cnt; }
          }
          LGKM0();
          if (l == 0) flags[4 + wk] = sigma;
          // ---- refill HBM prefetch slot ----
          const int tn = tau + 12;
          if (tn < len) {
            const float* g = gb + (size_t)tn * 1024;
#pragma unroll
            for (int k = 0; k < 16; ++k) buf[s][k] = g[k * 32];
          }
        }
      }
    }
    // final drain
    while (sigma <= len - 1) {
      for (;;) { int f0 = flags_nv[0]; MEMBAR(); if (f0 >= sigma) break; }
      DO_BP(sigma); sigma += 3;
      LGKM0();
      if (l == 0) flags[4 + wk] = sigma;
    }
  }
  __syncthreads();

  // ================== epilogue: mlp + last_tag ==================
  if (wid == 0) {
    float v = alphaH[((len - 1) & 31) * 32 + j];
    int idx = j;
#pragma unroll
    for (int d = 1; d <= 16; d <<= 1) {
      float ov = bperm_f(l ^ d, v);
      int   oi = bperm_i(l ^ d, idx);
      if (ov > v || (ov == v && oi < idx)) { v = ov; idx = oi; }  // first-index argmax
    }
    if (tid == 0) { out[b] = v; flags_nv[8] = idx; }
  }
  __syncthreads();
  const int last_tag = flags_nv[8];

  // ---- Phase A: per-chunk backpointer map composition (32 chunks of 64) ----
  int M[8];
#pragma unroll
  for (int m = 0; m < 8; ++m) M[m] = j;
  for (int kk = 63; kk >= 0; --kk) {
#pragma unroll
    for (int m = 0; m < 8; ++m) {
      const int c = wid * 8 + m;
      const int t = c * 64 + kk;
      if (t >= 1 && t < len) {             // t>=len: identity (masked steps)
        int bt = back[t * 32 + j];
        M[m] = bperm_i(M[m], bt);          // M <- back_t[M]
      }
    }
  }
#pragma unroll
  for (int m = 0; m < 8; ++m) if (l < 32) maps[(wid * 8 + m) * 32 + l] = (uint8_t)M[m];
  __syncthreads();

  // ---- Phase B: stitch chunk-boundary tags ----
  if (tid == 0) {
    int e = last_tag;
    Ev[31] = e;
    for (int c = 31; c >= 1; --c) { e = maps[c * 32 + e]; Ev[c - 1] = e; }
  }
  __syncthreads();

  // ---- Phase C: replay within chunks, emit tags ----
  int tg[8], kp[8];
#pragma unroll
  for (int m = 0; m < 8; ++m) { tg[m] = Ev[wid * 8 + m]; kp[m] = tg[m]; }
  for (int kk = 63; kk >= 0; --kk) {
#pragma unroll
    for (int m = 0; m < 8; ++m) {
      const int c = wid * 8 + m;
      const int p = c * 64 + kk;
      kp[m] = (l == kk) ? tg[m] : kp[m];   // lane kk keeps tag@p
      if (p >= 1 && p < len) {
        int bt = back[p * 32 + j];
        tg[m] = bperm_i(tg[m], bt);        // tag@(p-1) = back_p[tag@p]
      }
    }
  }
#pragma unroll
  for (int m = 0; m < 8; ++m) {
    const int c = wid * 8 + m;
    const int pos = c * 64 + l;
    out[64 + b * TT + pos] = (pos < len) ? (float)kp[m] : -1.0f;
  }
}

extern "C" void kernel_launch(void* const* d_in, const int* in_sizes, int n_in,
                              void* d_out, int out_size, void* d_ws, size_t ws_size,
                              hipStream_t stream) {
  const float* lp     = (const float*)d_in[0];
  const int*   mask   = (const int*)d_in[1];
  const int*   startc = (const int*)d_in[2];
  const int*   endc   = (const int*)d_in[3];
  const int*   transc = (const int*)d_in[4];
  float* out = (float*)d_out;
  (void)d_ws; (void)ws_size; (void)n_in; (void)in_sizes; (void)out_size;
  hipFuncSetAttribute((const void*)viterbi_fused,
                      hipFuncAttributeMaxDynamicSharedMemorySize, SMEM_BYTES);
  viterbi_fused<<<dim3(64), dim3(256), SMEM_BYTES, stream>>>(lp, mask, startc, endc, transc, out);
}